// Round 13
// baseline (166980.322 us; speedup 1.0000x reference)
//
#include <hip/hip_runtime.h>
#include <math.h>

#define Bsz 64
#define Tsz 1024
#define Esz 300
#define Hsz 200
#define Gsz 800   // 4*H
#define NTOK (Bsz*Tsz)
#define WPAD 6400

// NOTE: macro params must not collide with float4 member names x/y/z/w
#define FMA4(A_, W_, H_) do { \
  (A_).x = fmaf((W_).x, (H_), (A_).x); \
  (A_).y = fmaf((W_).y, (H_), (A_).y); \
  (A_).z = fmaf((W_).z, (H_), (A_).z); \
  (A_).w = fmaf((W_).w, (H_), (A_).w); } while (0)

// Gate permutation: interleaved index r' = 4*unit + gate  <->  original
// row origRow(r') = (r'%4)*200 + r'/4. P and WhhT both use the interleaved
// layout so one worker owns all 4 gates of its unit as one float4.

// ---------------- lengths: lens[b] = sum(mask[b,:]) ----------------
// mask may be 1-byte bool or 4-byte int. len >= 512 always, so byte[1]
// is 1 iff 1-byte layout.
__global__ __launch_bounds__(256) void k_lengths(const void* __restrict__ mraw,
                                                 int* __restrict__ lens) {
  __shared__ int red[256];
  const unsigned char* mb = (const unsigned char*)mraw;
  const int isbool = (mb[1] != 0);
  int b = blockIdx.x, tid = threadIdx.x;
  int s = 0;
  if (isbool) {
    const unsigned char* row = mb + (size_t)b * Tsz;
    for (int i = tid; i < Tsz; i += 256) s += (row[i] != 0);
  } else {
    const int* row = (const int*)mraw + (size_t)b * Tsz;
    for (int i = tid; i < Tsz; i += 256) s += (row[i] != 0);
  }
  red[tid] = s; __syncthreads();
  for (int off = 128; off; off >>= 1) {
    if (tid < off) red[tid] += red[tid + off];
    __syncthreads();
  }
  if (tid == 0) lens[b] = red[0];
}

// ---------------- Whh transpose + gate interleave ----------------------
// WhhT[k][r'] = Whh[origRow(r')][k]; written input-indexed:
// WhhT[j*Gsz + perm(r)] = Whh[r*Hsz + j], perm(r) = 4*(r%200) + r/200.
__global__ __launch_bounds__(256) void k_transpose(const float* __restrict__ Whh,
                                                   float* __restrict__ WhhT) {
  int idx = blockIdx.x * 256 + threadIdx.x;
  if (idx >= Gsz * Hsz) return;
  int r = idx / Hsz, j = idx - r * Hsz;
  int rp = 4 * (r % Hsz) + r / Hsz;
  WhhT[(size_t)j * Gsz + rp] = Whh[idx];
}

// ---------------- input projection GEMM, both directions (blockIdx.z) --
// Output column col holds gate origRow(col): we permute which W row (and
// bias entry) feeds each output column; stores stay fully coalesced.
#define BM 64
#define BN 160
#define BK 20
__global__ __launch_bounds__(256) void k_gemm(const int* __restrict__ x,
                                              const float* __restrict__ embed,
                                              const float* __restrict__ Wf,
                                              const float* __restrict__ biasf,
                                              const float* __restrict__ Wb_,
                                              const float* __restrict__ biasb,
                                              float* __restrict__ Pf,
                                              float* __restrict__ Pb,
                                              int t0f, int t0b, int tcShift) {
  __shared__ __align__(16) float As[BK][BM];
  __shared__ __align__(16) float Bs[BK][BN];
  __shared__ int toks[BM];
  const int revz = blockIdx.z;
  const float* __restrict__ W    = revz ? Wb_  : Wf;
  const float* __restrict__ bias = revz ? biasb : biasf;
  float* __restrict__ P          = revz ? Pb   : Pf;
  const int t0                   = revz ? t0b  : t0f;
  int tid = threadIdx.x;
  int n0 = blockIdx.x * BM;
  int j0 = blockIdx.y * BN;
  if (tid < BM) {
    int n = n0 + tid;
    int bb = n >> tcShift;
    int tl = n & ((1 << tcShift) - 1);
    toks[tid] = x[(bb << 10) + t0 + tl];
  }
  float acc[8][5];
#pragma unroll
  for (int i = 0; i < 8; i++)
#pragma unroll
    for (int j = 0; j < 5; j++) acc[i][j] = 0.f;
  int rg = tid >> 5;
  int cg = tid & 31;
  for (int k0 = 0; k0 < Esz; k0 += BK) {
    __syncthreads();
    for (int idx = tid; idx < BM * 5; idx += 256) {
      int r = idx / 5, q = idx % 5;
      const float4 v = *reinterpret_cast<const float4*>(
          embed + (size_t)toks[r] * Esz + k0 + q * 4);
      As[q * 4 + 0][r] = v.x; As[q * 4 + 1][r] = v.y;
      As[q * 4 + 2][r] = v.z; As[q * 4 + 3][r] = v.w;
    }
    for (int idx = tid; idx < BN * 5; idx += 256) {
      int j = idx / 5, q = idx % 5;
      int colg = j0 + j;
      int srcRow = (colg & 3) * Hsz + (colg >> 2);   // gate interleave
      const float4 v = *reinterpret_cast<const float4*>(
          W + (size_t)srcRow * Esz + k0 + q * 4);
      Bs[q * 4 + 0][j] = v.x; Bs[q * 4 + 1][j] = v.y;
      Bs[q * 4 + 2][j] = v.z; Bs[q * 4 + 3][j] = v.w;
    }
    __syncthreads();
#pragma unroll
    for (int kk = 0; kk < BK; ++kk) {
      float4 a0 = *reinterpret_cast<const float4*>(&As[kk][rg * 8]);
      float4 a1 = *reinterpret_cast<const float4*>(&As[kk][rg * 8 + 4]);
      float a[8] = {a0.x, a0.y, a0.z, a0.w, a1.x, a1.y, a1.z, a1.w};
      float bv[5];
#pragma unroll
      for (int j = 0; j < 5; j++) bv[j] = Bs[kk][cg + 32 * j];
#pragma unroll
      for (int i = 0; i < 8; i++)
#pragma unroll
        for (int j = 0; j < 5; j++) acc[i][j] = fmaf(a[i], bv[j], acc[i][j]);
    }
  }
#pragma unroll
  for (int j = 0; j < 5; j++) {
    int col = j0 + cg + 32 * j;
    float bb = bias[(col & 3) * Hsz + (col >> 2)];
#pragma unroll
    for (int i = 0; i < 8; i++) {
      int n = n0 + rg * 8 + i;
      P[(size_t)n * Gsz + col] = acc[i][j] + bb;
    }
  }
}

// ---------------- masked LSTM, unit-per-worker, 1 barrier/step ---------
// 128 WGs (bid<64 fwd, else bwd), 256 threads (4 waves, 1/SIMD -> 512-reg
// budget). Workers tid<200: worker u owns unit u entirely; acc float4 =
// (i,f,g,o) of unit u; loops over all 200 k. Weights per worker (200 f4):
//   k [0,96):    VGPR-resident (384 regs, loaded once)
//   k [96,144):  LDS-resident  (153.6 KB, [k][u] layout)
//   k [144,200): streamed per step (179 KB/step, 8-deep static ring)
// c stays in a register; h double-buffered in LDS by step parity ->
// exactly one __syncthreads() per step. redA/B parity-buffered; tid0's
// post-barrier read precedes any step-s+2 overwrite (barrier ordering).
__global__ __launch_bounds__(256, 1) void k_lstm(
    const float* __restrict__ Pf, const float* __restrict__ Pb,
    const float* __restrict__ WhhTf, const float* __restrict__ WhhTb,
    const int* __restrict__ lens,
    const float* __restrict__ Wa, const float* __restrict__ Wb,
    float* __restrict__ hcF, float* __restrict__ hcB,
    float* __restrict__ zaf, float* __restrict__ zbf,
    float* __restrict__ zab, float* __restrict__ zbb,
    int t0f, int t0b, int TC, int init) {
  __shared__ __align__(16) float4 wlds[48 * 200];   // 153600 B
  __shared__ __align__(16) float hbuf[2][200];      // h double buffer
  __shared__ float redA[2][4], redB[2][4];
  int bid = blockIdx.x, tid = threadIdx.x;
  int rev = bid >> 6;
  int b = bid & 63;
  int len = lens[b];
  const float* P    = rev ? Pb : Pf;
  const float* WhhT = rev ? WhhTb : WhhTf;
  float* hcb = (rev ? hcB : hcF) + (size_t)b * 2 * Hsz;
  float* za  = rev ? zab : zaf;
  float* zb  = rev ? zbb : zbf;
  int t0 = rev ? t0b : t0f;
  const int worker = (tid < 200);
  const int u = tid;
  float wa = 0.f, wb = 0.f, c0 = 0.f;
  const float4* __restrict__ wp4 =
      reinterpret_cast<const float4*>(WhhT) + (worker ? u : 0);
  float4 wreg[96];
  if (worker) {
    hbuf[0][u] = init ? 0.f : hcb[u];
    c0 = init ? 0.f : hcb[Hsz + u];
    int off = rev ? Hsz : 0;
    wa = Wa[off + u]; wb = Wb[off + u];
#pragma unroll
    for (int k = 0; k < 96; k++) wreg[k] = wp4[(size_t)k * 200];
#pragma unroll
    for (int i = 0; i < 48; i++)
      wlds[i * 200 + u] = wp4[(size_t)(96 + i) * 200];
  }
  __syncthreads();

  int lo = t0;
  int hi = t0 + TC; if (len < hi) hi = len;
  int nsteps = hi - lo; if (nsteps < 0) nsteps = 0;

  for (int s = 0; s < nsteps; ++s) {
    int par = s & 1;
    int t = rev ? (hi - 1 - s) : (lo + s);
    float pa = 0.f, pb = 0.f;
    if (worker) {
      float4 rbuf[8];
#pragma unroll
      for (int q = 0; q < 8; q++) rbuf[q] = wp4[(size_t)(144 + q) * 200];
      const float4* __restrict__ Prow4 = reinterpret_cast<const float4*>(
          P + ((size_t)b * TC + (t - t0)) * Gsz);
      float4 acc = Prow4[u];
      // phase 1: VGPR weights, k = 0..95 (h read as broadcast quads)
#pragma unroll
      for (int kq = 0; kq < 24; kq++) {
        float4 hv = *reinterpret_cast<const float4*>(&hbuf[par][4 * kq]);
        FMA4(acc, wreg[4 * kq + 0], hv.x);
        FMA4(acc, wreg[4 * kq + 1], hv.y);
        FMA4(acc, wreg[4 * kq + 2], hv.z);
        FMA4(acc, wreg[4 * kq + 3], hv.w);
      }
      // phase 2: LDS weights, k = 96..143
#pragma unroll
      for (int kq = 0; kq < 12; kq++) {
        float4 hv = *reinterpret_cast<const float4*>(&hbuf[par][96 + 4 * kq]);
        FMA4(acc, wlds[(4 * kq + 0) * 200 + u], hv.x);
        FMA4(acc, wlds[(4 * kq + 1) * 200 + u], hv.y);
        FMA4(acc, wlds[(4 * kq + 2) * 200 + u], hv.z);
        FMA4(acc, wlds[(4 * kq + 3) * 200 + u], hv.w);
      }
      // phase 3: streamed weights, k = 144..199, 8-deep static ring
#pragma unroll
      for (int q = 0; q < 56; q++) {
        float4 wv = rbuf[q & 7];
        if (q < 48) rbuf[q & 7] = wp4[(size_t)(152 + q) * 200];
        float hj = hbuf[par][144 + q];
        FMA4(acc, wv, hj);
      }
      // fused activation: acc = (i,f,g,o) of unit u; c in register
      float ig = 1.f / (1.f + expf(-acc.x));
      float fg = 1.f / (1.f + expf(-acc.y));
      float gt = tanhf(acc.z);
      float og = 1.f / (1.f + expf(-acc.w));
      float cn = fmaf(fg, c0, ig * gt);
      float hn = og * tanhf(cn);
      c0 = cn;
      hbuf[par ^ 1][u] = hn;
      pa = hn * wa; pb = hn * wb;
    }
#pragma unroll
    for (int off = 32; off; off >>= 1) {
      pa += __shfl_down(pa, off);
      pb += __shfl_down(pb, off);
    }
    if ((tid & 63) == 0) { redA[par][tid >> 6] = pa; redB[par][tid >> 6] = pb; }
    __syncthreads();   // h_new + red visible; ONE barrier per step
    if (tid == 0) {
      float sa = redA[par][0] + redA[par][1] + redA[par][2] + redA[par][3];
      float sb = redB[par][0] + redB[par][1] + redB[par][2] + redB[par][3];
      za[(size_t)b * Tsz + t] = sa;
      zb[(size_t)b * Tsz + t] = sb;
    }
  }
  if (worker) {
    hcb[u]       = hbuf[nsteps & 1][u];
    hcb[Hsz + u] = c0;
  }
}

// ---------------- Kuma head per token (double precision) ---------------
__global__ __launch_bounds__(256) void k_head(const float* __restrict__ zaf,
                                              const float* __restrict__ zbf,
                                              const float* __restrict__ zab,
                                              const float* __restrict__ zbb,
                                              const int* __restrict__ lens,
                                              const float* __restrict__ ba,
                                              const float* __restrict__ bb,
                                              float* __restrict__ zp) {
  int n = blockIdx.x * 256 + threadIdx.x;
  if (n >= NTOK) return;
  int b = n >> 10, t = n & 1023;
  if (t >= lens[b]) { zp[n] = 0.f; return; }
  double av = ((double)zaf[n] + (double)zab[n]) * 100.0 + (double)ba[0];
  double bv = ((double)zbf[n] + (double)zbb[n]) * 100.0 + (double)bb[0];
  double a  = av > 0.0 ? av + log1p(exp(-av)) : log1p(exp(av));
  double bk = bv > 0.0 ? bv + log1p(exp(-bv)) : log1p(exp(bv));
  a  = fmin(fmax(a, 1e-6), 100.0);
  bk = fmin(fmax(bk, 1e-6), 100.0);
  double ia = 1.0 + 1.0 / a;
  double lb = lgamma(ia) + lgamma(bk) - lgamma(ia + bk);
  double mean = bk * exp(lb);
  mean = -0.1 + 1.2 * mean;
  mean = fmin(fmax(mean, 0.0), 1.0);
  zp[n] = (float)mean;
}

// ---------------- stable top-k selection per row -----------------------
__global__ __launch_bounds__(256) void k_select(const float* __restrict__ zp,
                                                const int* __restrict__ lens,
                                                float* __restrict__ out) {
  __shared__ float zv[Tsz];
  __shared__ float wbv[4];
  __shared__ int wbi[4];
  __shared__ int stop;
  int b = blockIdx.x, tid = threadIdx.x;
  const float* row = zp + (size_t)b * Tsz;
  for (int i = tid; i < Tsz; i += 256) zv[i] = row[i];
  if (tid == 0) stop = 0;
  int len = lens[b];
  int k = (int)rintf(0.1f * (float)len);
  __syncthreads();
  for (int it = 0; it < k; ++it) {
    float bvl = -1.f; int bil = 0;
#pragma unroll
    for (int s = 0; s < 4; s++) {
      int i = tid * 4 + s;
      float v = zv[i];
      if (v > bvl) { bvl = v; bil = i; }
    }
    for (int off = 32; off; off >>= 1) {
      float ov = __shfl_down(bvl, off);
      int   oi = __shfl_down(bil, off);
      if (ov > bvl || (ov == bvl && oi < bil)) { bvl = ov; bil = oi; }
    }
    int w = tid >> 6;
    if ((tid & 63) == 0) { wbv[w] = bvl; wbi[w] = bil; }
    __syncthreads();
    if (tid == 0) {
      float fb = wbv[0]; int fi = wbi[0];
      for (int q = 1; q < 4; q++)
        if (wbv[q] > fb || (wbv[q] == fb && wbi[q] < fi)) { fb = wbv[q]; fi = wbi[q]; }
      if (fb <= 0.f) stop = 1;
      else { out[(size_t)b * Tsz + fi] = 1.0f; zv[fi] = -1e30f; }
    }
    __syncthreads();
    if (stop) break;
  }
}

extern "C" void kernel_launch(void* const* d_in, const int* in_sizes, int n_in,
                              void* d_out, int out_size, void* d_ws, size_t ws_size,
                              hipStream_t stream) {
  const int*   x      = (const int*)d_in[0];
  const void*  mask   = d_in[1];
  const float* embed  = (const float*)d_in[2];
  const float* Wih_f  = (const float*)d_in[3];
  const float* Whh_f  = (const float*)d_in[4];
  const float* b_f    = (const float*)d_in[5];
  const float* Wih_b  = (const float*)d_in[6];
  const float* Whh_b  = (const float*)d_in[7];
  const float* b_b    = (const float*)d_in[8];
  const float* Wa     = (const float*)d_in[9];
  const float* ba     = (const float*)d_in[10];
  const float* Wb     = (const float*)d_in[11];
  const float* bb     = (const float*)d_in[12];
  float* out = (float*)d_out;

  // ---- adaptive time-chunk: need TWO P buffers (fwd + bwd) ----
  size_t fixedBytes = (5 * (size_t)NTOK + 2 * (size_t)Bsz * 2 * Hsz +
                       2 * ((size_t)Hsz * Gsz + WPAD)) * sizeof(float) +
                      Bsz * sizeof(int) + 1024;
  int TC = 16;
  const int cand[7] = {1024, 512, 256, 128, 64, 32, 16};
  for (int i = 0; i < 7; i++) {
    size_t need = fixedBytes + 2 * (size_t)Bsz * cand[i] * Gsz * sizeof(float);
    if (need <= ws_size) { TC = cand[i]; break; }
  }
  int tcShift = 31 - __builtin_clz((unsigned)TC);

  float* Pf    = (float*)d_ws;                      // Bsz*TC*Gsz
  float* Pb    = Pf + (size_t)Bsz * TC * Gsz;       // Bsz*TC*Gsz
  float* zaf   = Pb + (size_t)Bsz * TC * Gsz;       // NTOK
  float* zbf   = zaf + NTOK;
  float* zab   = zbf + NTOK;
  float* zbb   = zab + NTOK;
  float* zp    = zbb + NTOK;
  float* hcF   = zp + NTOK;                         // Bsz*2*Hsz
  float* hcB   = hcF + (size_t)Bsz * 2 * Hsz;
  float* WhhTf = hcB + (size_t)Bsz * 2 * Hsz;       // Hsz*Gsz + WPAD
  float* WhhTb = WhhTf + (size_t)Hsz * Gsz + WPAD;
  int*   lens  = (int*)(WhhTb + (size_t)Hsz * Gsz + WPAD);

  k_lengths<<<Bsz, 256, 0, stream>>>(mask, lens);

  const int tgrid = (Gsz * Hsz + 255) / 256;
  k_transpose<<<tgrid, 256, 0, stream>>>(Whh_f, WhhTf);
  k_transpose<<<tgrid, 256, 0, stream>>>(Whh_b, WhhTb);

  int nch = Tsz / TC;
  dim3 gg((Bsz * TC) / BM, Gsz / BN, 2);
  for (int ci = 0; ci < nch; ++ci) {
    int t0f = ci * TC;
    int t0b = (nch - 1 - ci) * TC;
    k_gemm<<<gg, 256, 0, stream>>>(x, embed, Wih_f, b_f, Wih_b, b_b,
                                   Pf, Pb, t0f, t0b, tcShift);
    k_lstm<<<2 * Bsz, 256, 0, stream>>>(Pf, Pb, WhhTf, WhhTb, lens, Wa, Wb,
                                        hcF, hcB, zaf, zbf, zab, zbb,
                                        t0f, t0b, TC, ci == 0);
  }

  k_head<<<NTOK / 256, 256, 0, stream>>>(zaf, zbf, zab, zbb, lens, ba, bb, zp);

  (void)hipMemsetAsync(d_out, 0, (size_t)out_size * sizeof(float), stream);
  k_select<<<Bsz, 256, 0, stream>>>(zp, lens, out);
}

// Round 14
// 4268.248 us; speedup vs baseline: 39.1215x; 39.1215x over previous
//
#include <hip/hip_runtime.h>
#include <math.h>

#define Bsz 64
#define Tsz 1024
#define Esz 300
#define Hsz 200
#define Gsz 800   // 4*H
#define NTOK (Bsz*Tsz)
#define WPAD 6400

// NOTE: macro params must not collide with float4 member names x/y/z/w
#define FMA4(A_, W_, H_) do { \
  (A_).x = fmaf((W_).x, (H_), (A_).x); \
  (A_).y = fmaf((W_).y, (H_), (A_).y); \
  (A_).z = fmaf((W_).z, (H_), (A_).z); \
  (A_).w = fmaf((W_).w, (H_), (A_).w); } while (0)

// Gate-interleaved layout (validated r13): gate-vector f4 #u = (i,f,g,o)
// of unit u. interleaved row r' = 4*unit + gate; orig row = (r'%4)*200+r'/4.

// ---------------- lengths: lens[b] = sum(mask[b,:]) ----------------
__global__ __launch_bounds__(256) void k_lengths(const void* __restrict__ mraw,
                                                 int* __restrict__ lens) {
  __shared__ int red[256];
  const unsigned char* mb = (const unsigned char*)mraw;
  const int isbool = (mb[1] != 0);
  int b = blockIdx.x, tid = threadIdx.x;
  int s = 0;
  if (isbool) {
    const unsigned char* row = mb + (size_t)b * Tsz;
    for (int i = tid; i < Tsz; i += 256) s += (row[i] != 0);
  } else {
    const int* row = (const int*)mraw + (size_t)b * Tsz;
    for (int i = tid; i < Tsz; i += 256) s += (row[i] != 0);
  }
  red[tid] = s; __syncthreads();
  for (int off = 128; off; off >>= 1) {
    if (tid < off) red[tid] += red[tid + off];
    __syncthreads();
  }
  if (tid == 0) lens[b] = red[0];
}

// ---------------- Whh transpose + gate interleave (validated r13) ------
__global__ __launch_bounds__(256) void k_transpose(const float* __restrict__ Whh,
                                                   float* __restrict__ WhhT) {
  int idx = blockIdx.x * 256 + threadIdx.x;
  if (idx >= Gsz * Hsz) return;
  int r = idx / Hsz, j = idx - r * Hsz;
  int rp = 4 * (r % Hsz) + r / Hsz;
  WhhT[(size_t)j * Gsz + rp] = Whh[idx];
}

// ---------------- input projection GEMM, interleaved output ------------
#define BM 64
#define BN 160
#define BK 20
__global__ __launch_bounds__(256) void k_gemm(const int* __restrict__ x,
                                              const float* __restrict__ embed,
                                              const float* __restrict__ Wf,
                                              const float* __restrict__ biasf,
                                              const float* __restrict__ Wb_,
                                              const float* __restrict__ biasb,
                                              float* __restrict__ Pf,
                                              float* __restrict__ Pb,
                                              int t0f, int t0b, int tcShift) {
  __shared__ __align__(16) float As[BK][BM];
  __shared__ __align__(16) float Bs[BK][BN];
  __shared__ int toks[BM];
  const int revz = blockIdx.z;
  const float* __restrict__ W    = revz ? Wb_  : Wf;
  const float* __restrict__ bias = revz ? biasb : biasf;
  float* __restrict__ P          = revz ? Pb   : Pf;
  const int t0                   = revz ? t0b  : t0f;
  int tid = threadIdx.x;
  int n0 = blockIdx.x * BM;
  int j0 = blockIdx.y * BN;
  if (tid < BM) {
    int n = n0 + tid;
    int bb = n >> tcShift;
    int tl = n & ((1 << tcShift) - 1);
    toks[tid] = x[(bb << 10) + t0 + tl];
  }
  float acc[8][5];
#pragma unroll
  for (int i = 0; i < 8; i++)
#pragma unroll
    for (int j = 0; j < 5; j++) acc[i][j] = 0.f;
  int rg = tid >> 5;
  int cg = tid & 31;
  for (int k0 = 0; k0 < Esz; k0 += BK) {
    __syncthreads();
    for (int idx = tid; idx < BM * 5; idx += 256) {
      int r = idx / 5, q = idx % 5;
      const float4 v = *reinterpret_cast<const float4*>(
          embed + (size_t)toks[r] * Esz + k0 + q * 4);
      As[q * 4 + 0][r] = v.x; As[q * 4 + 1][r] = v.y;
      As[q * 4 + 2][r] = v.z; As[q * 4 + 3][r] = v.w;
    }
    for (int idx = tid; idx < BN * 5; idx += 256) {
      int j = idx / 5, q = idx % 5;
      int colg = j0 + j;
      int srcRow = (colg & 3) * Hsz + (colg >> 2);   // gate interleave
      const float4 v = *reinterpret_cast<const float4*>(
          W + (size_t)srcRow * Esz + k0 + q * 4);
      Bs[q * 4 + 0][j] = v.x; Bs[q * 4 + 1][j] = v.y;
      Bs[q * 4 + 2][j] = v.z; Bs[q * 4 + 3][j] = v.w;
    }
    __syncthreads();
#pragma unroll
    for (int kk = 0; kk < BK; ++kk) {
      float4 a0 = *reinterpret_cast<const float4*>(&As[kk][rg * 8]);
      float4 a1 = *reinterpret_cast<const float4*>(&As[kk][rg * 8 + 4]);
      float a[8] = {a0.x, a0.y, a0.z, a0.w, a1.x, a1.y, a1.z, a1.w};
      float bv[5];
#pragma unroll
      for (int j = 0; j < 5; j++) bv[j] = Bs[kk][cg + 32 * j];
#pragma unroll
      for (int i = 0; i < 8; i++)
#pragma unroll
        for (int j = 0; j < 5; j++) acc[i][j] = fmaf(a[i], bv[j], acc[i][j]);
    }
  }
#pragma unroll
  for (int j = 0; j < 5; j++) {
    int col = j0 + cg + 32 * j;
    float bb = bias[(col & 3) * Hsz + (col >> 2)];
#pragma unroll
    for (int i = 0; i < 8; i++) {
      int n = n0 + rg * 8 + i;
      P[(size_t)n * Gsz + col] = acc[i][j] + bb;
    }
  }
}

// ---------------- masked LSTM: r11 GEMV core + fused unit activation ---
// 128 WGs (bid<64 fwd, else bwd), 512 threads (8 waves). Workers tid<500:
// col = tid%100 owns interleaved-f4 pair {2col,2col+1} (= units 2col,
// 2col+1); gk = tid/100 owns k-slice [40gk,40gk+40). 80 slabs/worker, slab
// q at wp4[(q>>1)*200 + (q&1)]:
//   [0,40):  VGPR (160 regs)   [40,57): LDS (136 KB)   [57,80): streamed
//   (184 KB/step, 8-deep static ring, proven r10 shape)
// Phase 2 (tid<200): thread u reduces 5 partials of f4 #u = (i,f,g,o) of
// unit u -> fused activation; c[u] in register; h[u] single LDS buffer.
// TWO barriers/step (g4 roundtrip + 3rd barrier deleted vs r11).
__global__ __launch_bounds__(512, 2) void k_lstm(
    const float* __restrict__ Pf, const float* __restrict__ Pb,
    const float* __restrict__ WhhTf, const float* __restrict__ WhhTb,
    const int* __restrict__ lens,
    const float* __restrict__ Wa, const float* __restrict__ Wb,
    float* __restrict__ hcF, float* __restrict__ hcB,
    float* __restrict__ zaf, float* __restrict__ zbf,
    float* __restrict__ zab, float* __restrict__ zbb,
    int t0f, int t0b, int TC, int init) {
  __shared__ __align__(16) float h[Hsz];
  __shared__ __align__(16) float4 part[1000];   // [gk][200]
  __shared__ __align__(16) float4 wlds[8500];   // [17][500]
  __shared__ float redA[2][8], redB[2][8];
  int bid = blockIdx.x, tid = threadIdx.x;
  int rev = bid >> 6;
  int b = bid & 63;
  int len = lens[b];
  const float* P    = rev ? Pb : Pf;
  const float* WhhT = rev ? WhhTb : WhhTf;
  float* hcb = (rev ? hcB : hcF) + (size_t)b * 2 * Hsz;
  float* za  = rev ? zab : zaf;
  float* zb  = rev ? zbb : zbf;
  int t0 = rev ? t0b : t0f;
  float wa = 0.f, wb = 0.f, c0 = 0.f;
  if (tid < Hsz) {
    h[tid] = init ? 0.f : hcb[tid];
    c0     = init ? 0.f : hcb[Hsz + tid];
    int off = rev ? Hsz : 0;
    wa = Wa[off + tid]; wb = Wb[off + tid];
  }
  const int worker = (tid < 500);
  int col = 0, gk = 0;
  if (worker) { col = tid % 100; gk = tid / 100; }
  const int hbase = gk * 40;
  const float4* __restrict__ wp4 =
      reinterpret_cast<const float4*>(WhhT) + (size_t)hbase * 200 + 2 * col;

  // ---- load persistent weights (once per dispatch) ----
  float4 wreg[40];                       // slabs [0,40)
  if (worker) {
#pragma unroll
    for (int q = 0; q < 40; q++) wreg[q] = wp4[(q >> 1) * 200 + (q & 1)];
#pragma unroll
    for (int i = 0; i < 17; i++)         // slabs [40,57)
      wlds[i * 500 + tid] = wp4[((40 + i) >> 1) * 200 + ((40 + i) & 1)];
  }
  __syncthreads();

  int lo = t0;
  int hi = t0 + TC; if (len < hi) hi = len;
  int nsteps = hi - lo; if (nsteps < 0) nsteps = 0;

  for (int s = 0; s < nsteps; ++s) {
    int t = rev ? (hi - 1 - s) : (lo + s);
    const float4* __restrict__ Prow4 = reinterpret_cast<const float4*>(
        P + ((size_t)b * TC + (t - t0)) * Gsz);
    if (worker) {
      // issue ring slots early (slabs 57..64 in flight during resident fmas)
      float4 rbuf[8];
#pragma unroll
      for (int q = 0; q < 8; q++)
        rbuf[q] = wp4[((57 + q) >> 1) * 200 + ((57 + q) & 1)];
      float4 acc0, acc1;
      if (gk == 0) { acc0 = Prow4[2 * col]; acc1 = Prow4[2 * col + 1]; }
      else {
        acc0.x = acc0.y = acc0.z = acc0.w = 0.f;
        acc1.x = acc1.y = acc1.z = acc1.w = 0.f;
      }
      // phase 1: VGPR-resident slabs [0,40)
#pragma unroll
      for (int u = 0; u < 20; u++) {
        float hj = h[hbase + u];
        FMA4(acc0, wreg[2 * u], hj);
        FMA4(acc1, wreg[2 * u + 1], hj);
      }
      // phase 2: LDS-resident slabs [40,57): k-row 20+(i>>1), accsel i&1
#pragma unroll
      for (int i = 0; i < 17; i++) {
        float hj = h[hbase + 20 + (i >> 1)];
        float4 wv = wlds[i * 500 + tid];
        if (i & 1) { FMA4(acc1, wv, hj); } else { FMA4(acc0, wv, hj); }
      }
      // phase 3: streamed slabs [57,80), 8-deep static ring (23 slabs)
#pragma unroll
      for (int q = 0; q < 15; q++) {
        float4 wv = rbuf[q & 7];
        rbuf[q & 7] = wp4[((65 + q) >> 1) * 200 + ((65 + q) & 1)];
        float hj = h[hbase + ((57 + q) >> 1)];
        if ((57 + q) & 1) { FMA4(acc1, wv, hj); } else { FMA4(acc0, wv, hj); }
      }
#pragma unroll
      for (int q = 15; q < 23; q++) {
        float4 wv = rbuf[q & 7];
        float hj = h[hbase + ((57 + q) >> 1)];
        if ((57 + q) & 1) { FMA4(acc1, wv, hj); } else { FMA4(acc0, wv, hj); }
      }
      part[gk * 200 + 2 * col]     = acc0;
      part[gk * 200 + 2 * col + 1] = acc1;
    }
    __syncthreads();   // bar A: partials ready; phase-1 h reads complete
    float pa = 0.f, pb = 0.f;
    if (tid < Hsz) {
      float4 p0 = part[tid],       p1 = part[200 + tid], p2 = part[400 + tid];
      float4 p3 = part[600 + tid], p4 = part[800 + tid];
      float gi = p0.x + p1.x + p2.x + p3.x + p4.x;
      float gf = p0.y + p1.y + p2.y + p3.y + p4.y;
      float gc = p0.z + p1.z + p2.z + p3.z + p4.z;
      float go = p0.w + p1.w + p2.w + p3.w + p4.w;
      float ig = 1.f / (1.f + expf(-gi));
      float fg = 1.f / (1.f + expf(-gf));
      float gt = tanhf(gc);
      float og = 1.f / (1.f + expf(-go));
      float cn = fmaf(fg, c0, ig * gt);
      float hn = og * tanhf(cn);
      c0 = cn; h[tid] = hn;
      pa = hn * wa; pb = hn * wb;
    }
#pragma unroll
    for (int off = 32; off; off >>= 1) {
      pa += __shfl_down(pa, off);
      pb += __shfl_down(pb, off);
    }
    if ((tid & 63) == 0) { redA[s & 1][tid >> 6] = pa; redB[s & 1][tid >> 6] = pb; }
    __syncthreads();   // bar B: h + red visible for next step
    if (tid == 0) {
      float sa = 0.f, sb = 0.f;
#pragma unroll
      for (int w = 0; w < 8; ++w) { sa += redA[s & 1][w]; sb += redB[s & 1][w]; }
      za[(size_t)b * Tsz + t] = sa;
      zb[(size_t)b * Tsz + t] = sb;
    }
  }
  if (tid < Hsz) { hcb[tid] = h[tid]; hcb[Hsz + tid] = c0; }
}

// ---------------- Kuma head per token (double precision) ---------------
__global__ __launch_bounds__(256) void k_head(const float* __restrict__ zaf,
                                              const float* __restrict__ zbf,
                                              const float* __restrict__ zab,
                                              const float* __restrict__ zbb,
                                              const int* __restrict__ lens,
                                              const float* __restrict__ ba,
                                              const float* __restrict__ bb,
                                              float* __restrict__ zp) {
  int n = blockIdx.x * 256 + threadIdx.x;
  if (n >= NTOK) return;
  int b = n >> 10, t = n & 1023;
  if (t >= lens[b]) { zp[n] = 0.f; return; }
  double av = ((double)zaf[n] + (double)zab[n]) * 100.0 + (double)ba[0];
  double bv = ((double)zbf[n] + (double)zbb[n]) * 100.0 + (double)bb[0];
  double a  = av > 0.0 ? av + log1p(exp(-av)) : log1p(exp(av));
  double bk = bv > 0.0 ? bv + log1p(exp(-bv)) : log1p(exp(bv));
  a  = fmin(fmax(a, 1e-6), 100.0);
  bk = fmin(fmax(bk, 1e-6), 100.0);
  double ia = 1.0 + 1.0 / a;
  double lb = lgamma(ia) + lgamma(bk) - lgamma(ia + bk);
  double mean = bk * exp(lb);
  mean = -0.1 + 1.2 * mean;
  mean = fmin(fmax(mean, 0.0), 1.0);
  zp[n] = (float)mean;
}

// ---------------- stable top-k selection per row -----------------------
__global__ __launch_bounds__(256) void k_select(const float* __restrict__ zp,
                                                const int* __restrict__ lens,
                                                float* __restrict__ out) {
  __shared__ float zv[Tsz];
  __shared__ float wbv[4];
  __shared__ int wbi[4];
  __shared__ int stop;
  int b = blockIdx.x, tid = threadIdx.x;
  const float* row = zp + (size_t)b * Tsz;
  for (int i = tid; i < Tsz; i += 256) zv[i] = row[i];
  if (tid == 0) stop = 0;
  int len = lens[b];
  int k = (int)rintf(0.1f * (float)len);
  __syncthreads();
  for (int it = 0; it < k; ++it) {
    float bvl = -1.f; int bil = 0;
#pragma unroll
    for (int s = 0; s < 4; s++) {
      int i = tid * 4 + s;
      float v = zv[i];
      if (v > bvl) { bvl = v; bil = i; }
    }
    for (int off = 32; off; off >>= 1) {
      float ov = __shfl_down(bvl, off);
      int   oi = __shfl_down(bil, off);
      if (ov > bvl || (ov == bvl && oi < bil)) { bvl = ov; bil = oi; }
    }
    int w = tid >> 6;
    if ((tid & 63) == 0) { wbv[w] = bvl; wbi[w] = bil; }
    __syncthreads();
    if (tid == 0) {
      float fb = wbv[0]; int fi = wbi[0];
      for (int q = 1; q < 4; q++)
        if (wbv[q] > fb || (wbv[q] == fb && wbi[q] < fi)) { fb = wbv[q]; fi = wbi[q]; }
      if (fb <= 0.f) stop = 1;
      else { out[(size_t)b * Tsz + fi] = 1.0f; zv[fi] = -1e30f; }
    }
    __syncthreads();
    if (stop) break;
  }
}

extern "C" void kernel_launch(void* const* d_in, const int* in_sizes, int n_in,
                              void* d_out, int out_size, void* d_ws, size_t ws_size,
                              hipStream_t stream) {
  const int*   x      = (const int*)d_in[0];
  const void*  mask   = d_in[1];
  const float* embed  = (const float*)d_in[2];
  const float* Wih_f  = (const float*)d_in[3];
  const float* Whh_f  = (const float*)d_in[4];
  const float* b_f    = (const float*)d_in[5];
  const float* Wih_b  = (const float*)d_in[6];
  const float* Whh_b  = (const float*)d_in[7];
  const float* b_b    = (const float*)d_in[8];
  const float* Wa     = (const float*)d_in[9];
  const float* ba     = (const float*)d_in[10];
  const float* Wb     = (const float*)d_in[11];
  const float* bb     = (const float*)d_in[12];
  float* out = (float*)d_out;

  // ---- adaptive time-chunk: need TWO P buffers (fwd + bwd) ----
  size_t fixedBytes = (5 * (size_t)NTOK + 2 * (size_t)Bsz * 2 * Hsz +
                       2 * ((size_t)Hsz * Gsz + WPAD)) * sizeof(float) +
                      Bsz * sizeof(int) + 1024;
  int TC = 16;
  const int cand[7] = {1024, 512, 256, 128, 64, 32, 16};
  for (int i = 0; i < 7; i++) {
    size_t need = fixedBytes + 2 * (size_t)Bsz * cand[i] * Gsz * sizeof(float);
    if (need <= ws_size) { TC = cand[i]; break; }
  }
  int tcShift = 31 - __builtin_clz((unsigned)TC);

  float* Pf    = (float*)d_ws;                      // Bsz*TC*Gsz
  float* Pb    = Pf + (size_t)Bsz * TC * Gsz;       // Bsz*TC*Gsz
  float* zaf   = Pb + (size_t)Bsz * TC * Gsz;       // NTOK
  float* zbf   = zaf + NTOK;
  float* zab   = zbf + NTOK;
  float* zbb   = zab + NTOK;
  float* zp    = zbb + NTOK;
  float* hcF   = zp + NTOK;                         // Bsz*2*Hsz
  float* hcB   = hcF + (size_t)Bsz * 2 * Hsz;
  float* WhhTf = hcB + (size_t)Bsz * 2 * Hsz;       // Hsz*Gsz + WPAD
  float* WhhTb = WhhTf + (size_t)Hsz * Gsz + WPAD;
  int*   lens  = (int*)(WhhTb + (size_t)Hsz * Gsz + WPAD);

  k_lengths<<<Bsz, 256, 0, stream>>>(mask, lens);

  const int tgrid = (Gsz * Hsz + 255) / 256;
  k_transpose<<<tgrid, 256, 0, stream>>>(Whh_f, WhhTf);
  k_transpose<<<tgrid, 256, 0, stream>>>(Whh_b, WhhTb);

  int nch = Tsz / TC;
  dim3 gg((Bsz * TC) / BM, Gsz / BN, 2);
  for (int ci = 0; ci < nch; ++ci) {
    int t0f = ci * TC;
    int t0b = (nch - 1 - ci) * TC;
    k_gemm<<<gg, 256, 0, stream>>>(x, embed, Wih_f, b_f, Wih_b, b_b,
                                   Pf, Pb, t0f, t0b, tcShift);
    k_lstm<<<2 * Bsz, 512, 0, stream>>>(Pf, Pb, WhhTf, WhhTb, lens, Wa, Wb,
                                        hcF, hcB, zaf, zbf, zab, zbb,
                                        t0f, t0b, TC, ci == 0);
  }

  k_head<<<NTOK / 256, 256, 0, stream>>>(zaf, zbf, zab, zbb, lens, ba, bb, zp);

  (void)hipMemsetAsync(d_out, 0, (size_t)out_size * sizeof(float), stream);
  k_select<<<Bsz, 256, 0, stream>>>(zp, lens, out);
}

// Round 15
// 3588.382 us; speedup vs baseline: 46.5336x; 1.1895x over previous
//
#include <hip/hip_runtime.h>
#include <math.h>

#define Bsz 64
#define Tsz 1024
#define Esz 300
#define Hsz 200
#define Gsz 800   // 4*H
#define NTOK (Bsz*Tsz)
#define WPAD 6400

// NOTE: macro params must not collide with float4 member names x/y/z/w
#define FMA4(A_, W_, H_) do { \
  (A_).x = fmaf((W_).x, (H_), (A_).x); \
  (A_).y = fmaf((W_).y, (H_), (A_).y); \
  (A_).z = fmaf((W_).z, (H_), (A_).z); \
  (A_).w = fmaf((W_).w, (H_), (A_).w); } while (0)

// Gate-interleaved layout (validated r13/r14): f4 #u = (i,f,g,o) of unit u.
// interleaved row r' = 4*unit + gate; orig row = (r'%4)*200 + r'/4.

// ---------------- lengths ----------------
__global__ __launch_bounds__(256) void k_lengths(const void* __restrict__ mraw,
                                                 int* __restrict__ lens) {
  __shared__ int red[256];
  const unsigned char* mb = (const unsigned char*)mraw;
  const int isbool = (mb[1] != 0);
  int b = blockIdx.x, tid = threadIdx.x;
  int s = 0;
  if (isbool) {
    const unsigned char* row = mb + (size_t)b * Tsz;
    for (int i = tid; i < Tsz; i += 256) s += (row[i] != 0);
  } else {
    const int* row = (const int*)mraw + (size_t)b * Tsz;
    for (int i = tid; i < Tsz; i += 256) s += (row[i] != 0);
  }
  red[tid] = s; __syncthreads();
  for (int off = 128; off; off >>= 1) {
    if (tid < off) red[tid] += red[tid + off];
    __syncthreads();
  }
  if (tid == 0) lens[b] = red[0];
}

// ---------------- Whh transpose + gate interleave ----------------------
__global__ __launch_bounds__(256) void k_transpose(const float* __restrict__ Whh,
                                                   float* __restrict__ WhhT) {
  int idx = blockIdx.x * 256 + threadIdx.x;
  if (idx >= Gsz * Hsz) return;
  int r = idx / Hsz, j = idx - r * Hsz;
  int rp = 4 * (r % Hsz) + r / Hsz;
  WhhT[(size_t)j * Gsz + rp] = Whh[idx];
}

// ---------------- standalone input-projection GEMM (pre-chunk/fallback) -
#define BM 64
#define BN 160
#define BK 20
__global__ __launch_bounds__(256) void k_gemm(const int* __restrict__ x,
                                              const float* __restrict__ embed,
                                              const float* __restrict__ Wf,
                                              const float* __restrict__ biasf,
                                              const float* __restrict__ Wb_,
                                              const float* __restrict__ biasb,
                                              float* __restrict__ Pf,
                                              float* __restrict__ Pb,
                                              int t0f, int t0b, int tcShift) {
  __shared__ __align__(16) float As[BK][BM];
  __shared__ __align__(16) float Bs[BK][BN];
  __shared__ int toks[BM];
  const int revz = blockIdx.z;
  const float* __restrict__ W    = revz ? Wb_  : Wf;
  const float* __restrict__ bias = revz ? biasb : biasf;
  float* __restrict__ P          = revz ? Pb   : Pf;
  const int t0                   = revz ? t0b  : t0f;
  int tid = threadIdx.x;
  int n0 = blockIdx.x * BM;
  int j0 = blockIdx.y * BN;
  if (tid < BM) {
    int n = n0 + tid;
    toks[tid] = x[((n >> tcShift) << 10) + t0 + (n & ((1 << tcShift) - 1))];
  }
  float acc[8][5];
#pragma unroll
  for (int i = 0; i < 8; i++)
#pragma unroll
    for (int j = 0; j < 5; j++) acc[i][j] = 0.f;
  int rg = tid >> 5;
  int cg = tid & 31;
  for (int k0 = 0; k0 < Esz; k0 += BK) {
    __syncthreads();
    for (int idx = tid; idx < BM * 5; idx += 256) {
      int r = idx / 5, q = idx % 5;
      const float4 v = *reinterpret_cast<const float4*>(
          embed + (size_t)toks[r] * Esz + k0 + q * 4);
      As[q * 4 + 0][r] = v.x; As[q * 4 + 1][r] = v.y;
      As[q * 4 + 2][r] = v.z; As[q * 4 + 3][r] = v.w;
    }
    for (int idx = tid; idx < BN * 5; idx += 256) {
      int j = idx / 5, q = idx % 5;
      int colg = j0 + j;
      int srcRow = (colg & 3) * Hsz + (colg >> 2);
      const float4 v = *reinterpret_cast<const float4*>(
          W + (size_t)srcRow * Esz + k0 + q * 4);
      Bs[q * 4 + 0][j] = v.x; Bs[q * 4 + 1][j] = v.y;
      Bs[q * 4 + 2][j] = v.z; Bs[q * 4 + 3][j] = v.w;
    }
    __syncthreads();
#pragma unroll
    for (int kk = 0; kk < BK; ++kk) {
      float4 a0 = *reinterpret_cast<const float4*>(&As[kk][rg * 8]);
      float4 a1 = *reinterpret_cast<const float4*>(&As[kk][rg * 8 + 4]);
      float a[8] = {a0.x, a0.y, a0.z, a0.w, a1.x, a1.y, a1.z, a1.w};
      float bv[5];
#pragma unroll
      for (int j = 0; j < 5; j++) bv[j] = Bs[kk][cg + 32 * j];
#pragma unroll
      for (int i = 0; i < 8; i++)
#pragma unroll
        for (int j = 0; j < 5; j++) acc[i][j] = fmaf(a[i], bv[j], acc[i][j]);
    }
  }
#pragma unroll
  for (int j = 0; j < 5; j++) {
    int col = j0 + cg + 32 * j;
    float bb = bias[(col & 3) * Hsz + (col >> 2)];
#pragma unroll
    for (int i = 0; i < 8; i++) {
      int n = n0 + rg * 8 + i;
      P[(size_t)n * Gsz + col] = acc[i][j] + bb;
    }
  }
}

// ---------------- fused: LSTM(chunk i) || GEMM(chunk i+1) --------------
// 512 threads. bid<128: lstm (r14 core, 18 LDS slabs). bid>=128: GEMM for
// the NEXT chunk on the CUs the lstm leaves idle (lstm LDS=157KB -> 1
// WG/CU -> 128 CUs free). GEMM path: BM2=128 x BN=160, 8x5 micro-tile,
// 512 thr; shares LDS by aliasing into wlds. Kernel boundary = sync:
// P(next) complete before next fused dispatch reads it.
#define BM2 128
__global__ __launch_bounds__(512, 2) void k_fused(
    const float* __restrict__ Pf, const float* __restrict__ Pb,
    const float* __restrict__ WhhTf, const float* __restrict__ WhhTb,
    const int* __restrict__ lens,
    const float* __restrict__ Wa, const float* __restrict__ Wb,
    float* __restrict__ hcF, float* __restrict__ hcB,
    float* __restrict__ zaf, float* __restrict__ zbf,
    float* __restrict__ zab, float* __restrict__ zbb,
    int t0f, int t0b, int TC, int tcShift, int init,
    const int* __restrict__ x, const float* __restrict__ embed,
    const float* __restrict__ Wihf, const float* __restrict__ bf,
    const float* __restrict__ Wihb, const float* __restrict__ bb_,
    float* __restrict__ PfN, float* __restrict__ PbN,
    int t0fN, int t0bN, int gemmValid) {
  __shared__ __align__(16) float h[Hsz];
  __shared__ __align__(16) float4 part[1000];   // [gk][200]
  __shared__ __align__(16) float4 wlds[9000];   // [18][500] resident weights
  __shared__ float redA[2][8], redB[2][8];
  int bid = blockIdx.x, tid = threadIdx.x;

  if (bid >= 128) {
    // ================= GEMM path (next chunk, both dirs) ================
    if (!gemmValid) return;
    float* As = reinterpret_cast<float*>(wlds);          // [20][128]
    float* Bs = As + BK * BM2;                           // [20][160]
    int*  toks = reinterpret_cast<int*>(Bs + BK * BN);   // [128]
    int gid = bid - 128;
    int dir = gid / 640;
    int rem = gid - dir * 640;
    int gy = rem / 128;
    int gx = rem - gy * 128;
    const float* __restrict__ W    = dir ? Wihb : Wihf;
    const float* __restrict__ bias = dir ? bb_  : bf;
    float* __restrict__ P          = dir ? PbN  : PfN;
    const int t0                   = dir ? t0bN : t0fN;
    int n0 = gx * BM2;
    int j0 = gy * BN;
    if (tid < BM2) {
      int n = n0 + tid;
      toks[tid] = x[((n >> tcShift) << 10) + t0 + (n & ((1 << tcShift) - 1))];
    }
    float acc[8][5];
#pragma unroll
    for (int i = 0; i < 8; i++)
#pragma unroll
      for (int j = 0; j < 5; j++) acc[i][j] = 0.f;
    int rg = tid >> 5;    // 0..15, 8 rows each
    int cg = tid & 31;
    for (int k0 = 0; k0 < Esz; k0 += BK) {
      __syncthreads();
      for (int idx = tid; idx < BM2 * 5; idx += 512) {
        int r = idx / 5, q = idx % 5;
        const float4 v = *reinterpret_cast<const float4*>(
            embed + (size_t)toks[r] * Esz + k0 + q * 4);
        As[(q * 4 + 0) * BM2 + r] = v.x; As[(q * 4 + 1) * BM2 + r] = v.y;
        As[(q * 4 + 2) * BM2 + r] = v.z; As[(q * 4 + 3) * BM2 + r] = v.w;
      }
      for (int idx = tid; idx < BN * 5; idx += 512) {
        int j = idx / 5, q = idx % 5;
        int colg = j0 + j;
        int srcRow = (colg & 3) * Hsz + (colg >> 2);
        const float4 v = *reinterpret_cast<const float4*>(
            W + (size_t)srcRow * Esz + k0 + q * 4);
        Bs[(q * 4 + 0) * BN + j] = v.x; Bs[(q * 4 + 1) * BN + j] = v.y;
        Bs[(q * 4 + 2) * BN + j] = v.z; Bs[(q * 4 + 3) * BN + j] = v.w;
      }
      __syncthreads();
#pragma unroll
      for (int kk = 0; kk < BK; ++kk) {
        float4 a0 = *reinterpret_cast<const float4*>(&As[kk * BM2 + rg * 8]);
        float4 a1 = *reinterpret_cast<const float4*>(&As[kk * BM2 + rg * 8 + 4]);
        float a[8] = {a0.x, a0.y, a0.z, a0.w, a1.x, a1.y, a1.z, a1.w};
        float bv[5];
#pragma unroll
        for (int j = 0; j < 5; j++) bv[j] = Bs[kk * BN + cg + 32 * j];
#pragma unroll
        for (int i = 0; i < 8; i++)
#pragma unroll
          for (int j = 0; j < 5; j++) acc[i][j] = fmaf(a[i], bv[j], acc[i][j]);
      }
    }
#pragma unroll
    for (int j = 0; j < 5; j++) {
      int col = j0 + cg + 32 * j;
      float bb = bias[(col & 3) * Hsz + (col >> 2)];
#pragma unroll
      for (int i = 0; i < 8; i++) {
        int n = n0 + rg * 8 + i;
        P[(size_t)n * Gsz + col] = acc[i][j] + bb;
      }
    }
    return;
  }

  // ================= LSTM path (r14 core + 18 LDS slabs) ================
  int rev = bid >> 6;
  int b = bid & 63;
  int len = lens[b];
  const float* P    = rev ? Pb : Pf;
  const float* WhhT = rev ? WhhTb : WhhTf;
  float* hcb = (rev ? hcB : hcF) + (size_t)b * 2 * Hsz;
  float* za  = rev ? zab : zaf;
  float* zb  = rev ? zbb : zbf;
  int t0 = rev ? t0b : t0f;
  float wa = 0.f, wb = 0.f, c0 = 0.f;
  if (tid < Hsz) {
    h[tid] = init ? 0.f : hcb[tid];
    c0     = init ? 0.f : hcb[Hsz + tid];
    int off = rev ? Hsz : 0;
    wa = Wa[off + tid]; wb = Wb[off + tid];
  }
  const int worker = (tid < 500);
  int col = 0, gk = 0;
  if (worker) { col = tid % 100; gk = tid / 100; }
  const int hbase = gk * 40;
  const float4* __restrict__ wp4 =
      reinterpret_cast<const float4*>(WhhT) + (size_t)hbase * 200 + 2 * col;

  // slabs [0,40) VGPR, [40,58) LDS, [58,80) streamed (176 KB/step)
  float4 wreg[40];
  if (worker) {
#pragma unroll
    for (int q = 0; q < 40; q++) wreg[q] = wp4[(q >> 1) * 200 + (q & 1)];
#pragma unroll
    for (int i = 0; i < 18; i++)
      wlds[i * 500 + tid] = wp4[((40 + i) >> 1) * 200 + ((40 + i) & 1)];
  }
  __syncthreads();

  int lo = t0;
  int hi = t0 + TC; if (len < hi) hi = len;
  int nsteps = hi - lo; if (nsteps < 0) nsteps = 0;

  for (int s = 0; s < nsteps; ++s) {
    int t = rev ? (hi - 1 - s) : (lo + s);
    const float4* __restrict__ Prow4 = reinterpret_cast<const float4*>(
        P + ((size_t)b * TC + (t - t0)) * Gsz);
    if (worker) {
      float4 rbuf[8];
#pragma unroll
      for (int q = 0; q < 8; q++)
        rbuf[q] = wp4[((58 + q) >> 1) * 200 + ((58 + q) & 1)];
      float4 acc0, acc1;
      if (gk == 0) { acc0 = Prow4[2 * col]; acc1 = Prow4[2 * col + 1]; }
      else {
        acc0.x = acc0.y = acc0.z = acc0.w = 0.f;
        acc1.x = acc1.y = acc1.z = acc1.w = 0.f;
      }
#pragma unroll
      for (int u = 0; u < 20; u++) {
        float hj = h[hbase + u];
        FMA4(acc0, wreg[2 * u], hj);
        FMA4(acc1, wreg[2 * u + 1], hj);
      }
#pragma unroll
      for (int i = 0; i < 18; i++) {
        float hj = h[hbase + 20 + (i >> 1)];
        float4 wv = wlds[i * 500 + tid];
        if (i & 1) { FMA4(acc1, wv, hj); } else { FMA4(acc0, wv, hj); }
      }
#pragma unroll
      for (int q = 0; q < 14; q++) {
        float4 wv = rbuf[q & 7];
        rbuf[q & 7] = wp4[((66 + q) >> 1) * 200 + ((66 + q) & 1)];
        float hj = h[hbase + ((58 + q) >> 1)];
        if ((58 + q) & 1) { FMA4(acc1, wv, hj); } else { FMA4(acc0, wv, hj); }
      }
#pragma unroll
      for (int q = 14; q < 22; q++) {
        float4 wv = rbuf[q & 7];
        float hj = h[hbase + ((58 + q) >> 1)];
        if ((58 + q) & 1) { FMA4(acc1, wv, hj); } else { FMA4(acc0, wv, hj); }
      }
      part[gk * 200 + 2 * col]     = acc0;
      part[gk * 200 + 2 * col + 1] = acc1;
    }
    __syncthreads();   // bar A: partials ready; phase-1 h reads complete
    float pa = 0.f, pb = 0.f;
    if (tid < Hsz) {
      float4 p0 = part[tid],       p1 = part[200 + tid], p2 = part[400 + tid];
      float4 p3 = part[600 + tid], p4 = part[800 + tid];
      float gi = p0.x + p1.x + p2.x + p3.x + p4.x;
      float gf = p0.y + p1.y + p2.y + p3.y + p4.y;
      float gc = p0.z + p1.z + p2.z + p3.z + p4.z;
      float go = p0.w + p1.w + p2.w + p3.w + p4.w;
      float ig = 1.f / (1.f + expf(-gi));
      float fg = 1.f / (1.f + expf(-gf));
      float gt = tanhf(gc);
      float og = 1.f / (1.f + expf(-go));
      float cn = fmaf(fg, c0, ig * gt);
      float hn = og * tanhf(cn);
      c0 = cn; h[tid] = hn;
      pa = hn * wa; pb = hn * wb;
    }
#pragma unroll
    for (int off = 32; off; off >>= 1) {
      pa += __shfl_down(pa, off);
      pb += __shfl_down(pb, off);
    }
    if ((tid & 63) == 0) { redA[s & 1][tid >> 6] = pa; redB[s & 1][tid >> 6] = pb; }
    __syncthreads();   // bar B: h + red visible for next step
    if (tid == 0) {
      float sa = 0.f, sb = 0.f;
#pragma unroll
      for (int w = 0; w < 8; ++w) { sa += redA[s & 1][w]; sb += redB[s & 1][w]; }
      za[(size_t)b * Tsz + t] = sa;
      zb[(size_t)b * Tsz + t] = sb;
    }
  }
  if (tid < Hsz) { hcb[tid] = h[tid]; hcb[Hsz + tid] = c0; }
}

// ---------------- Kuma head per token (double precision) ---------------
__global__ __launch_bounds__(256) void k_head(const float* __restrict__ zaf,
                                              const float* __restrict__ zbf,
                                              const float* __restrict__ zab,
                                              const float* __restrict__ zbb,
                                              const int* __restrict__ lens,
                                              const float* __restrict__ ba,
                                              const float* __restrict__ bb,
                                              float* __restrict__ zp) {
  int n = blockIdx.x * 256 + threadIdx.x;
  if (n >= NTOK) return;
  int b = n >> 10, t = n & 1023;
  if (t >= lens[b]) { zp[n] = 0.f; return; }
  double av = ((double)zaf[n] + (double)zab[n]) * 100.0 + (double)ba[0];
  double bv = ((double)zbf[n] + (double)zbb[n]) * 100.0 + (double)bb[0];
  double a  = av > 0.0 ? av + log1p(exp(-av)) : log1p(exp(av));
  double bk = bv > 0.0 ? bv + log1p(exp(-bv)) : log1p(exp(bv));
  a  = fmin(fmax(a, 1e-6), 100.0);
  bk = fmin(fmax(bk, 1e-6), 100.0);
  double ia = 1.0 + 1.0 / a;
  double lb = lgamma(ia) + lgamma(bk) - lgamma(ia + bk);
  double mean = bk * exp(lb);
  mean = -0.1 + 1.2 * mean;
  mean = fmin(fmax(mean, 0.0), 1.0);
  zp[n] = (float)mean;
}

// ---------------- stable top-k selection per row -----------------------
__global__ __launch_bounds__(256) void k_select(const float* __restrict__ zp,
                                                const int* __restrict__ lens,
                                                float* __restrict__ out) {
  __shared__ float zv[Tsz];
  __shared__ float wbv[4];
  __shared__ int wbi[4];
  __shared__ int stop;
  int b = blockIdx.x, tid = threadIdx.x;
  const float* row = zp + (size_t)b * Tsz;
  for (int i = tid; i < Tsz; i += 256) zv[i] = row[i];
  if (tid == 0) stop = 0;
  int len = lens[b];
  int k = (int)rintf(0.1f * (float)len);
  __syncthreads();
  for (int it = 0; it < k; ++it) {
    float bvl = -1.f; int bil = 0;
#pragma unroll
    for (int s = 0; s < 4; s++) {
      int i = tid * 4 + s;
      float v = zv[i];
      if (v > bvl) { bvl = v; bil = i; }
    }
    for (int off = 32; off; off >>= 1) {
      float ov = __shfl_down(bvl, off);
      int   oi = __shfl_down(bil, off);
      if (ov > bvl || (ov == bvl && oi < bil)) { bvl = ov; bil = oi; }
    }
    int w = tid >> 6;
    if ((tid & 63) == 0) { wbv[w] = bvl; wbi[w] = bil; }
    __syncthreads();
    if (tid == 0) {
      float fb = wbv[0]; int fi = wbi[0];
      for (int q = 1; q < 4; q++)
        if (wbv[q] > fb || (wbv[q] == fb && wbi[q] < fi)) { fb = wbv[q]; fi = wbi[q]; }
      if (fb <= 0.f) stop = 1;
      else { out[(size_t)b * Tsz + fi] = 1.0f; zv[fi] = -1e30f; }
    }
    __syncthreads();
    if (stop) break;
  }
}

extern "C" void kernel_launch(void* const* d_in, const int* in_sizes, int n_in,
                              void* d_out, int out_size, void* d_ws, size_t ws_size,
                              hipStream_t stream) {
  const int*   x      = (const int*)d_in[0];
  const void*  mask   = d_in[1];
  const float* embed  = (const float*)d_in[2];
  const float* Wih_f  = (const float*)d_in[3];
  const float* Whh_f  = (const float*)d_in[4];
  const float* b_f    = (const float*)d_in[5];
  const float* Wih_b  = (const float*)d_in[6];
  const float* Whh_b  = (const float*)d_in[7];
  const float* b_b    = (const float*)d_in[8];
  const float* Wa     = (const float*)d_in[9];
  const float* ba     = (const float*)d_in[10];
  const float* Wb     = (const float*)d_in[11];
  const float* bb     = (const float*)d_in[12];
  float* out = (float*)d_out;

  size_t fixedBytes = (5 * (size_t)NTOK + 2 * (size_t)Bsz * 2 * Hsz +
                       2 * ((size_t)Hsz * Gsz + WPAD)) * sizeof(float) +
                      Bsz * sizeof(int) + 1024;
  const int TCo = 256;
  size_t chunkFlO = (size_t)Bsz * TCo * Gsz;
  size_t needOverlap = fixedBytes + 4 * chunkFlO * sizeof(float);
  int overlap = (ws_size >= needOverlap);

  int TC = TCo, tcShift = 8, nP = 4;
  if (!overlap) {
    const int cand[5] = {256, 128, 64, 32, 16};
    for (int i = 0; i < 5; i++) {
      size_t need = fixedBytes + 2 * (size_t)Bsz * cand[i] * Gsz * sizeof(float);
      if (need <= ws_size) { TC = cand[i]; break; }
    }
    tcShift = 31 - __builtin_clz((unsigned)TC);
    nP = 2;
  }
  size_t chunkFl = (size_t)Bsz * TC * Gsz;

  float* Pbase = (float*)d_ws;
  float* PfA[2], *PbA[2];
  if (overlap) {
    PfA[0] = Pbase;               PfA[1] = Pbase + chunkFl;
    PbA[0] = Pbase + 2 * chunkFl; PbA[1] = Pbase + 3 * chunkFl;
  } else {
    PfA[0] = PfA[1] = Pbase;
    PbA[0] = PbA[1] = Pbase + chunkFl;
  }
  float* rest  = Pbase + nP * chunkFl;
  float* zaf   = rest;
  float* zbf   = zaf + NTOK;
  float* zab   = zbf + NTOK;
  float* zbb   = zab + NTOK;
  float* zp    = zbb + NTOK;
  float* hcF   = zp + NTOK;
  float* hcB   = hcF + (size_t)Bsz * 2 * Hsz;
  float* WhhTf = hcB + (size_t)Bsz * 2 * Hsz;
  float* WhhTb = WhhTf + (size_t)Hsz * Gsz + WPAD;
  int*   lens  = (int*)(WhhTb + (size_t)Hsz * Gsz + WPAD);

  k_lengths<<<Bsz, 256, 0, stream>>>(mask, lens);
  const int tgrid = (Gsz * Hsz + 255) / 256;
  k_transpose<<<tgrid, 256, 0, stream>>>(Whh_f, WhhTf);
  k_transpose<<<tgrid, 256, 0, stream>>>(Whh_b, WhhTb);

  int nch = Tsz / TC;
  if (overlap) {
    // pre-GEMM: fwd chunk 0 (t0=0) and bwd chunk 0 (t0=768) into parity 0
    dim3 gg((Bsz * TC) / BM, Gsz / BN, 2);
    k_gemm<<<gg, 256, 0, stream>>>(x, embed, Wih_f, b_f, Wih_b, b_b,
                                   PfA[0], PbA[0], 0, (nch - 1) * TC, tcShift);
    for (int i = 0; i < nch; ++i) {
      int gv = (i < nch - 1);
      int grid = 128 + (gv ? 1280 : 0);
      k_fused<<<grid, 512, 0, stream>>>(
          PfA[i & 1], PbA[i & 1], WhhTf, WhhTb, lens, Wa, Wb, hcF, hcB,
          zaf, zbf, zab, zbb, i * TC, (nch - 1 - i) * TC, TC, tcShift, i == 0,
          x, embed, Wih_f, b_f, Wih_b, b_b,
          PfA[(i + 1) & 1], PbA[(i + 1) & 1],
          (i + 1) * TC, (nch - 2 - i) * TC, gv);
    }
  } else {
    dim3 gg((Bsz * TC) / BM, Gsz / BN, 2);
    for (int i = 0; i < nch; ++i) {
      k_gemm<<<gg, 256, 0, stream>>>(x, embed, Wih_f, b_f, Wih_b, b_b,
                                     PfA[0], PbA[0], i * TC,
                                     (nch - 1 - i) * TC, tcShift);
      k_fused<<<128, 512, 0, stream>>>(
          PfA[0], PbA[0], WhhTf, WhhTb, lens, Wa, Wb, hcF, hcB,
          zaf, zbf, zab, zbb, i * TC, (nch - 1 - i) * TC, TC, tcShift, i == 0,
          x, embed, Wih_f, b_f, Wih_b, b_b, PfA[0], PbA[0], 0, 0, 0);
    }
  }

  k_head<<<NTOK / 256, 256, 0, stream>>>(zaf, zbf, zab, zbb, lens, ba, bb, zp);

  (void)hipMemsetAsync(d_out, 0, (size_t)out_size * sizeof(float), stream);
  k_select<<<Bsz, 256, 0, stream>>>(zp, lens, out);
}